// Round 10
// baseline (126.113 us; speedup 1.0000x reference)
//
#include <hip/hip_runtime.h>

// Regime-switching KF — R9 base (quad + Y-slab + z3-masked tail hoists)
// with CHAIN SURGERY (all math-identical):
//  (1) S-carry/ep-carry: carry predicted covariance row Sr = (B P B^T + Q)
//      row j and predicted mean epJ across steps; collapse tail computes
//      Sr_next = bb'*tmp + Q, epJ_next = bS*neJ. Step front starts at
//      M = S*g + 1 — ~2 serial levels removed from the un-hideable front.
//  (2) merged reduction: quad11 = ydy - qsum(z3(epJ*(uy+uJ) + uJ*tJ))
//      (qsum linear; removes one full qsum chain).
//  (3) Mq re-association: q11e is the only late input -> late chain pays
//      1 fmax instead of 2.
//  (4) sProws carried (P-row sums as collapse temps) so the twin's sP
//      hoist is unchanged.
// Lane-3 safety invariant unchanged: every escaping qsum is z3-masked;
// lane-3 value stream is a reordering of the proven-finite R0/R8 stream.

typedef float v2f __attribute__((ext_vector_type(2)));

static __device__ __forceinline__ float frcp(float x)  { return __builtin_amdgcn_rcpf(x); }
static __device__ __forceinline__ float frsq(float x)  { return __builtin_amdgcn_rsqf(x); }
static __device__ __forceinline__ float fexp2(float x) { return __builtin_amdgcn_exp2f(x); }
static __device__ __forceinline__ float flog2(float x) { return __builtin_amdgcn_logf(x); }

template <int CTRL>
static __device__ __forceinline__ float dppf(float x) {
    int i = __float_as_int(x);
    i = __builtin_amdgcn_mov_dpp(i, CTRL, 0xF, 0xF, true);
    return __int_as_float(i);
}
#define ROTL 0xC9   // quad_perm [1,2,0,3]: lane j reads lane j+1 (mod 3)
#define ROTR 0xD2   // quad_perm [2,0,1,3]: lane j reads lane j+2
#define XOR1 0xB1   // quad_perm [1,0,3,2]
#define XOR2 0x4E   // quad_perm [2,3,0,1]

static __device__ __forceinline__ float qsum(float x) {   // sum over the quad
    x += dppf<XOR1>(x);
    x += dppf<XOR2>(x);
    return x;
}

#define EPSF   1e-9f
#define L2E    1.4426950408889634f    // log2(e)
#define LN2    0.6931471805599453f
#define L2_2PI_9 23.86346461225016f   // 9*log2(2*pi)
#define C12F   1.00001e-4f            // (1 - 0.9999) + 1e-9
#define P22F   0.99990001f            // 0.9999 + 1e-9
#define QK     (-0.5f * L2E)

__global__ __launch_bounds__(64, 1)
void kf_kernel(const float* __restrict__ y,      // y[n][t][o]
               const float* __restrict__ pBG, const float* __restrict__ pBT,
               const float* __restrict__ pBB, const float* __restrict__ pBW,
               const float* __restrict__ lam1, const float* __restrict__ lam2,
               const float* __restrict__ qd,  const float* __restrict__ rd,
               const float* __restrict__ pG1, const float* __restrict__ pG2,
               float* __restrict__ partial, int N, int Nt)
{
    const int lane = threadIdx.x;
    const int j    = lane & 3;                     // 0..2 = factor row; 3 = aux
    const int sid  = (blockIdx.x * 64 + lane) >> 2;
    const bool valid = (sid < N);
    const bool isRow = (j < 3);
    const int jj = isRow ? j : 0;
    const int rowlen = Nt * 9;                     // 576
    const int nchunk = Nt / 4;

    // ---- wave-uniform setup ----
    const float bg = pBG[0], bt = pBT[0], bb = pBB[0], bw = pBW[0];
    float a[9], l2v[9], id[9], ld[9];
    a[0] = 1.f; a[1] = lam1[0]; a[2] = lam1[1];
    a[3] = 1.f; a[4] = lam1[2]; a[5] = lam1[3];
    a[6] = 1.f; a[7] = lam1[4]; a[8] = lam1[5];
    l2v[0] = 1.f;
    #pragma unroll
    for (int i = 0; i < 8; ++i) l2v[i + 1] = lam2[i];
    float l2detD = 0.f;
    #pragma unroll
    for (int o = 0; o < 9; ++o) {
        float dv = fabsf(rd[o]) + 1.0e-4f + 1.0e-5f;   // R diag + jitter
        id[o] = 1.0f / dv;
        ld[o] = l2v[o] * id[o];
        l2detD += flog2(dv);
    }
    const float q0 = fabsf(qd[0]) + 1e-4f, q1 = fabsf(qd[1]) + 1e-4f;
    const float q2 = fabsf(qd[2]) + 1e-4f, q3 = fabsf(qd[3]) + 1e-4f;
    const float g0 = a[0]*a[0]*id[0] + a[1]*a[1]*id[1] + a[2]*a[2]*id[2];
    const float g1 = a[3]*a[3]*id[3] + a[4]*a[4]*id[4] + a[5]*a[5]*id[5];
    const float g2 = a[6]*a[6]*id[6] + a[7]*a[7]*id[7] + a[8]*a[8]*id[8];
    float h = 0.f;
    #pragma unroll
    for (int o = 0; o < 9; ++o) h += l2v[o] * ld[o];
    const float pk0 = q0 / (1.f + q0 * g0);
    const float pk1 = q1 / (1.f + q1 * g1);
    const float pk2 = q2 / (1.f + q2 * g2);
    const float C12D = C12F * frsq((1.f + q0*g0) * (1.f + q1*g1) * (1.f + q2*g2));
    const float gam1 = pG1[0], w0c = pG2[0], w1c = pG2[1], w2c = pG2[2];
    const float CC = -0.5f * (l2detD + L2_2PI_9);
    const float bw2 = bw * bw;

    // ---- per-lane selected constants (jj = own factor / triplet index) ----
    auto sel3 = [&](float x0, float x1, float x2) {
        float r = (jj == 1) ? x1 : x0;
        return (jj == 2) ? x2 : r;
    };
    const float aO0 = sel3(a[0], a[3], a[6]), aO1 = sel3(a[1], a[4], a[7]), aO2 = sel3(a[2], a[5], a[8]);
    const float iO0 = sel3(id[0], id[3], id[6]), iO1 = sel3(id[1], id[4], id[7]), iO2 = sel3(id[2], id[5], id[8]);
    const float lO0 = sel3(ld[0], ld[3], ld[6]), lO1 = sel3(ld[1], ld[4], ld[7]), lO2 = sel3(ld[2], ld[5], ld[8]);
    const float bS = sel3(bg, bt, bb), bN = sel3(bt, bb, bg), bP = sel3(bb, bg, bt);
    const float bS2 = bS*bS, bSN = bS*bN, bSP = bS*bP;
    const float gS = sel3(g0, g1, g2), gN = sel3(g1, g2, g0), gP = sel3(g2, g0, g1);
    const float qS = sel3(q0, q1, q2);
    const float pkS = sel3(pk0, pk1, pk2);
    const float wS = sel3(w0c, w1c, w2c);

    auto z3 = [&](float x) { return isRow ? x : 0.0f; };   // NaN-safe lane-3 mask

    // ---- state (S-carry form) ----
    float pf1 = 0.99f + EPSF, pf2 = 0.01f + EPSF;          // dup
    float seJ = 0.f;                                       // eta1[j]
    float epJ = 0.f;                                       // bS*seJ (carried)
    // Sr = predicted covariance row j (relative): S = B P B^T + Q
    float Sr0 = bS2*1000.f + qS, Sr1 = 0.f, Sr2 = 0.f;     // from P0 = 1000 I
    float sProws = 1000.f;                                 // P row sums (for sP hoist)
    float sm2 = 0.f, sp2 = 1e-9f;                          // dup
    float acc2 = 0.0f;

    // ---- hoisted state-only quantities (recomputed at each step's tail) ----
    float pp1h, w21h, w22h, c12h;
    v2f m2h, puh;
    auto hoist = [&]() {
        float logit = gam1 + qsum(z3(wS * seJ));
        float esig = fexp2(-logit * L2E);
        float p11 = frcp(1.f + esig);
        pp1h = pf1 * (p11 + EPSF);
        float pp2 = pf1 * (1.f - p11 + EPSF);
        float seS = qsum(z3(seJ));
        float sP  = qsum(z3(sProws));
        m2h.x = seS * (1.f/3.f);
        m2h.y = bw * sm2;
        v2f pvv; pvv.x = q3 + sP * (1.f/9.f); pvv.y = bw2*sp2 + q3;
        v2f rvv; rvv.x = frsq(1.f + pvv.x*h); rvv.y = frsq(1.f + pvv.y*h);
        puh = pvv * (rvv * rvv);
        w21h = pp2 * rvv.x;
        w22h = (pf2 * P22F) * rvv.y;
        c12h = pf2 * C12D;
    };

    // ---- staging: each lane reads its own 3-obs triplet per step ----
    const float* row = y + (size_t)(valid ? sid : 0) * rowlen + 3 * jj;
    float A[12], B[12];
    auto loadChunk = [&](float (&buf)[12], int c) {
        const float* p = row + c * 36;
        #pragma unroll
        for (int s = 0; s < 4; ++s) {
            buf[s*3+0] = p[s*9+0];
            buf[s*3+1] = p[s*9+1];
            buf[s*3+2] = p[s*9+2];
        }
    };
    loadChunk(A, 0);

    // input-only slab for a 4-step chunk: uy (== u12), f = pkS*uy, ydy, yl,
    // q12e. Pure functions of the observation row.
    struct YB4 { float uy[4], f[4], ydy[4], yl[4], q12e[4]; };
    auto computeYB4 = [&](YB4& o, const float (&buf)[12]) {
        #pragma unroll
        for (int s = 0; s < 4; ++s) {
            const float y0 = buf[s*3+0], y1 = buf[s*3+1], y2 = buf[s*3+2];
            float w0 = iO0*y0, w1 = iO1*y1, w2 = iO2*y2;
            float uy = aO0*w0 + aO1*w1 + aO2*w2;
            float ydy = qsum(z3(w0*y0 + w1*y1 + w2*y2));
            float yl  = qsum(z3(lO0*y0 + lO1*y1 + lO2*y2));
            float f = pkS * uy;
            float q12 = qsum(z3(pkS * uy * uy));
            o.uy[s] = uy; o.f[s] = f; o.ydy[s] = ydy; o.yl[s] = yl;
            o.q12e[s] = QK * (ydy - q12);
        }
    };

    auto step4 = [&](const YB4& yb) {
        #pragma unroll
        for (int s = 0; s < 4; ++s) {
            const float uy = yb.uy[s], fJ = yb.f[s];
            const float ydy = yb.ydy[s], yl = yb.yl[s], q12e = yb.q12e[s];

            // front: M row directly from carried S row (chain-shortened)
            float M0 = Sr0*gS + 1.f;
            float M1 = Sr1*gN;
            float M2 = Sr2*gP;
            float uJ = uy - gS * epJ;
            float r1c = epJ * (uy + uJ);        // early part of merged qsum

            // 3x3: gather other M rows, cross-product cofactor row, local det
            float Mn0 = dppf<ROTL>(M0), Mn1 = dppf<ROTL>(M1), Mn2 = dppf<ROTL>(M2);
            float Mp0 = dppf<ROTR>(M0), Mp1 = dppf<ROTR>(M1), Mp2 = dppf<ROTR>(M2);
            float cf0 = Mn0*Mp0 - Mn1*Mp2;
            float cf1 = Mn1*Mp1 - Mn2*Mp0;
            float cf2 = Mn2*Mp2 - Mn0*Mp1;
            float det = M0*cf0 + M1*cf1 + M2*cf2;   // det(M) >= 1
            float rs  = frsq(det);
            float iM  = rs * rs;                    // 1/det
            float cn0 = dppf<ROTL>(cf0), cn1 = dppf<ROTL>(cf1), cn2 = dppf<ROTL>(cf2);
            float cp0 = dppf<ROTR>(cf0), cp1 = dppf<ROTR>(cf1), cp2 = dppf<ROTR>(cf2);
            // Ci row j = (S * cof) row j / det  (N = S*cof symmetric)
            float Ci0 = iM * (Sr0*cf0 + Sr1*cn2 + Sr2*cp1);
            float Ci1 = iM * (Sr0*cf1 + Sr1*cn0 + Sr2*cp2);
            float Ci2 = iM * (Sr0*cf2 + Sr1*cn1 + Sr2*cp0);

            // t = Ci u ; merged quad11 = ydy - qsum(z3(r1c + uJ*tJ))
            float uN = dppf<ROTL>(uJ), uP = dppf<ROTR>(uJ);
            float tJ = Ci0*uJ + Ci1*uN + Ci2*uP;
            float quad11 = ydy - qsum(z3(fmaf(uJ, tJ, r1c)));
            float euJ = epJ + tJ;

            // regime-2 twin likelihood part (priors m2h/puh hoisted)
            v2f u1v  = (v2f){yl, yl} - m2h * (v2f){h, h};
            v2f vdav = (v2f){ydy, ydy} - m2h * ((v2f){2.f*yl, 2.f*yl} - m2h * (v2f){h, h});
            v2f pu1 = puh * u1v;
            v2f quadv = vdav - pu1 * u1v;
            v2f euv = m2h + pu1;

            // mixing (q11e is the only LATE input to Mq — re-associated)
            float q11e = QK * quad11;
            float q21e = QK * quadv.x, q22e = QK * quadv.y;
            float Mqe = fmaxf(fmaxf(q12e, q21e), q22e);
            float Mq = fmaxf(q11e, Mqe);
            float w11 = pp1h * rs * fexp2(q11e - Mq);
            float w12 = c12h      * fexp2(q12e - Mq);
            float w21 = w21h      * fexp2(q21e - Mq);
            float w22 = w22h      * fexp2(q22e - Mq);
            float ssum = w11 + w12 + w21 + w22;
            acc2 += Mq + flog2(ssum);
            float pr1n = w11 + w12, pr2n = w21 + w22;
            float den1 = pr1n + EPSF * ssum, den2 = pr2n + EPSF * ssum;
            float inv1 = frcp(den1), inv2 = frcp(den2), issum = frcp(ssum);
            float W11 = w11*inv1, W12 = w12*inv1;
            float W21 = w21*inv2, W22 = w22*inv2;
            pf1 = pr1n * issum + EPSF;
            pf2 = pr2n * issum + EPSF;

            // collapse regime 1 (row form) -> P temps -> scale to next S row
            float neJ = W11*euJ + W12*fJ;
            float daJ = euJ - neJ, dbJ = fJ - neJ;
            float daN = dppf<ROTL>(daJ), daP = dppf<ROTR>(daJ);
            float dbN = dppf<ROTL>(dbJ), dbP = dppf<ROTR>(dbJ);
            float t0 = W11*(Ci0 + daJ*daJ) + W12*(pkS + dbJ*dbJ);
            float t1 = W11*(Ci1 + daJ*daN) + W12*(dbJ*dbN);
            float t2 = W11*(Ci2 + daJ*daP) + W12*(dbJ*dbP);
            sProws = t0 + t1 + t2;                 // P row sums (sP hoist)
            Sr0 = bS2*t0 + qS;                     // S = B P B^T + Q, row j
            Sr1 = bSN*t1;
            Sr2 = bSP*t2;
            seJ = neJ;
            epJ = bS * neJ;                        // predicted mean (carried)

            // collapse regime 2 (dup)
            float nm2 = W21*euv.x + W22*euv.y;
            float dc = euv.x - nm2, dd = euv.y - nm2;
            sp2 = W21*(puh.x + dc*dc) + W22*(puh.y + dd*dd);
            sm2 = nm2;

            // tail: recompute all state-only hoisted quantities (z3-masked)
            hoist();
        }
    };

    hoist();                                   // initial-state hoist
    YB4 ya, yb;
    computeYB4(ya, A);
    for (int c = 0; c < nchunk; c += 2) {
        if (c + 1 < nchunk) loadChunk(B, c + 1);
        step4(ya);
        if (c + 1 < nchunk) computeYB4(yb, B);
        if (c + 2 < nchunk) loadChunk(A, c + 2);
        if (c + 1 < nchunk) step4(yb);
        if (c + 2 < nchunk) computeYB4(ya, A);
    }

    // one result per series (sublane 0), wave-reduce, one partial per block
    float acc = (valid && j == 0) ? (acc2 + (float)Nt * CC) * LN2 : 0.0f;
    #pragma unroll
    for (int off = 32; off; off >>= 1) acc += __shfl_down(acc, off, 64);
    if (lane == 0) partial[blockIdx.x] = acc;
}

__global__ __launch_bounds__(64)
void reduce_k(const float* __restrict__ part, float* __restrict__ out, int nb)
{
    float s = 0.f;
    for (int i = threadIdx.x; i < nb; i += 64) s += part[i];
    #pragma unroll
    for (int off = 32; off; off >>= 1) s += __shfl_down(s, off, 64);
    if (threadIdx.x == 0) out[0] = s;
}

extern "C" void kernel_launch(void* const* d_in, const int* in_sizes, int n_in,
                              void* d_out, int out_size, void* d_ws, size_t ws_size,
                              hipStream_t stream)
{
    const float* y    = (const float*)d_in[0];
    const float* pBG  = (const float*)d_in[1];
    const float* pBT  = (const float*)d_in[2];
    const float* pBB  = (const float*)d_in[3];
    const float* pBW  = (const float*)d_in[4];
    const float* lam1 = (const float*)d_in[5];
    const float* lam2 = (const float*)d_in[6];
    const float* qd   = (const float*)d_in[7];
    const float* rd   = (const float*)d_in[8];
    const float* pG1  = (const float*)d_in[9];
    const float* pG2  = (const float*)d_in[10];

    const int total = in_sizes[0];
    const int Nt = 64, O = 9;
    const int N = total / (Nt * O);
    const int blocks = (N * 4 + 63) / 64;    // 4 lanes per series

    float* partial = (float*)d_ws;
    kf_kernel<<<blocks, 64, 0, stream>>>(y, pBG, pBT, pBB, pBW, lam1, lam2,
                                         qd, rd, pG1, pG2, partial, N, Nt);
    reduce_k<<<1, 64, 0, stream>>>(partial, (float*)d_out, blocks);
}